// Round 3
// baseline (168.337 us; speedup 1.0000x reference)
//
#include <hip/hip_runtime.h>
#include <hip/hip_fp16.h>

#define POOLED 7
#define RATIO 2

constexpr int C_ = 256;
constexpr int H_ = 192;
constexpr int W_ = 192;
constexpr int P_ = H_ * W_;           // pixels per plane
constexpr int PP2 = POOLED * POOLED;  // 49

// ---------------- NCHW fp32 -> NHWC fp16 transpose -------------------------
constexpr int TC = 32;
constexpr int TP = 128;
constexpr int TPAD = TP + 1;

__global__ __launch_bounds__(256)
void nchw_to_nhwc_h(const float* __restrict__ in, __half* __restrict__ outT) {
    __shared__ float tile[TC][TPAD];
    const int b  = blockIdx.z;
    const int p0 = blockIdx.x * TP;
    const int c0 = blockIdx.y * TC;
    const float* src = in   + (size_t)b * C_ * P_;
    __half*      dst = outT + (size_t)b * P_ * C_;

    const int t = threadIdx.x;

    #pragma unroll
    for (int k = 0; k < 4; ++k) {
        const int q  = t + 256 * k;
        const int c  = q >> 5;
        const int pv = q & 31;
        const float4 v = *(const float4*)&src[(size_t)(c0 + c) * P_ + p0 + 4 * pv];
        tile[c][4 * pv + 0] = v.x;
        tile[c][4 * pv + 1] = v.y;
        tile[c][4 * pv + 2] = v.z;
        tile[c][4 * pv + 3] = v.w;
    }
    __syncthreads();

    #pragma unroll
    for (int k = 0; k < 2; ++k) {
        const int q  = t + 256 * k;
        const int p  = q >> 2;
        const int c8 = (q & 3) * 8;
        union { __half h[8]; float4 f; } u;
        #pragma unroll
        for (int i = 0; i < 8; ++i) u.h[i] = __float2half(tile[c8 + i][p]);
        *(float4*)&dst[(size_t)(p0 + p) * C_ + c0 + c8] = u.f;
    }
}

// ---------------- ROI batch partition (device prepass) ----------------------
// Builds two index lists (batch 0 / batch 1) so the main kernel can pin each
// (batch, channel-quarter) slice to one XCD class (blockIdx % 8). Order within
// a list is irrelevant (each job writes a disjoint output region).
__global__ __launch_bounds__(1024)
void roi_partition(const float* __restrict__ rois, int N,
                   int* __restrict__ lists,     // [2][N]
                   int* __restrict__ counts) {  // [2]
    __shared__ int cnt[2];
    const int t    = threadIdx.x;
    const int lane = t & 63;
    if (t < 2) cnt[t] = 0;
    __syncthreads();

    for (int i = t; i < N; i += 1024) {
        const int b = ((int)rois[(size_t)i * 5]) & 1;
        const unsigned long long m0 = __ballot(b == 0);
        const unsigned long long m1 = __ballot(b == 1);
        const unsigned long long mine = b ? m1 : m0;
        const int first = __ffsll((long long)mine) - 1;   // leader lane of my group
        const int rank  = __popcll(mine & ((1ull << lane) - 1ull));
        int base = 0;
        if (lane == first) base = atomicAdd(&cnt[b], (int)__popcll(mine));
        base = __shfl(base, first, 64);
        lists[b * N + base + rank] = i;
    }
    __syncthreads();
    if (t < 2) counts[t] = cnt[t];
}

// ---------------- RoIAlign on NHWC fp16 ------------------------------------
// Round-3: XCD/L2 locality theory. The feature map factors into 8 disjoint
// 4.7 MB slices: {batch 0,1} x {channel quarter 0..3} (each pixel's 512 B is
// 4 line-disjoint 128 B quarters). Class = blockIdx & 7 -> one slice per XCD
// (blocks round-robin across the 8 XCDs), so each XCD's gather working set
// ~= its private 4 MB L2. Gathers then served at L2 agg BW instead of L3.
// Inner loop identical to round 2 (corner-spread gather, depth-1 prefetch).
constexpr int CB  = 64;               // channels per block
constexpr int BPR = C_ / CB;          // 4 blocks per ROI
constexpr int BST = CB + 2;           // 66 halves: conflict-free half2 writes

__global__ __launch_bounds__(256, 8)
void roi_align_nhwc_h(const float* __restrict__ rois,
                      const __half* __restrict__ featT,   // (B,H,W,C) fp16
                      const int* __restrict__ stride_ptr,
                      const int* __restrict__ lists,      // [2][N]
                      const int* __restrict__ counts,     // [2]
                      float* __restrict__ out, int N) {
    __shared__ __half lds_out[PP2 * BST];  // 6468 B
    __shared__ int4 coord[28];             // [0..13]=y {lo*W, hi*W, frac*0.5, valid}
                                           // [14..27]=x {lo, hi, frac*0.5, valid}

    const int t    = threadIdx.x;
    const int lane = t & 63;
    const int wave = t >> 6;             // 0..3

    const int cls  = blockIdx.x & 7;     // XCD class
    const int bsel = cls >> 2;           // batch half (0/1)
    const int cq   = cls & 3;            // channel quarter
    const int nb   = counts[bsel];
    const int slots = (int)(gridDim.x >> 3);

    const float scale = 1.0f / (float)stride_ptr[0];

    const int cl4   = cq * (CB / 8) + (lane & 7);  // uint4 channel index
    const int g     = lane >> 3;                   // pixel-slot 0..7
    const int sxsel = g >> 2;                      // x-sample 0/1
    const int ysel  = (g >> 1) & 1;                // corner y lo/hi
    const int xsel  = g & 1;                       // corner x lo/hi

    for (int j = (int)(blockIdx.x >> 3); j < nb; j += slots) {
        const int n = lists[bsel * N + j];

        const float* r = rois + (size_t)n * 5;
        const int   b   = (int)r[0];
        const float rx1 = r[1] * scale;
        const float ry1 = r[2] * scale;
        const float rx2 = r[3] * scale;
        const float ry2 = r[4] * scale;
        const float bin_w = fmaxf(rx2 - rx1, 1.0f) * (1.0f / (float)POOLED);
        const float bin_h = fmaxf(ry2 - ry1, 1.0f) * (1.0f / (float)POOLED);

        if (t < 28) {
            const bool  isY   = t < 14;
            const int   s     = isY ? t : t - 14;
            const float start = isY ? ry1 : rx1;
            const float bsz   = isY ? bin_h : bin_w;
            const int   size  = isY ? H_ : W_;
            const float cc0   = start + ((float)s + 0.5f) * 0.5f * bsz;
            const bool  valid = (cc0 > -1.0f) && (cc0 < (float)size);
            float cc = fminf(fmaxf(cc0, 0.0f), (float)(size - 1));
            int lo = (int)floorf(cc);
            if (lo > size - 1) lo = size - 1;
            const int hi = min(lo + 1, size - 1);
            const float frac = (cc - (float)lo) * 0.5f;   // fold mean/4
            int4 e;
            e.x = isY ? lo * W_ : lo;
            e.y = isY ? hi * W_ : hi;
            e.z = __float_as_int(frac);
            e.w = valid ? 1 : 0;
            coord[t] = e;
        }
        __syncthreads();

        const uint4* fbase = (const uint4*)featT + (size_t)b * P_ * (C_ / 8);

        auto mkbin = [&](int bin, int& o0, int& o1, __half2& w0, __half2& w1) {
            const int ph = bin / POOLED;
            const int pw = bin - ph * POOLED;
            const int4  cx  = coord[14 + 2 * pw + sxsel];
            const float fx  = __int_as_float(cx.z);
            const float wx  = xsel ? fx : 0.5f - fx;
            const int   col = xsel ? cx.y : cx.x;

            const int4  cy0  = coord[2 * ph + 0];
            const float fy0  = __int_as_float(cy0.z);
            float wf0 = (ysel ? fy0 : 0.5f - fy0) * wx;
            if (!(cy0.w & cx.w)) wf0 = 0.0f;
            o0 = ((ysel ? cy0.y : cy0.x) + col) * (C_ / 8) + cl4;
            w0 = __float2half2_rn(wf0);

            const int4  cy1  = coord[2 * ph + 1];
            const float fy1  = __int_as_float(cy1.z);
            float wf1 = (ysel ? fy1 : 0.5f - fy1) * wx;
            if (!(cy1.w & cx.w)) wf1 = 0.0f;
            o1 = ((ysel ? cy1.y : cy1.x) + col) * (C_ / 8) + cl4;
            w1 = __float2half2_rn(wf1);
        };

        auto compute_store = [&](int bin, const uint4& A, const uint4& B,
                                 __half2 W0, __half2 W1) {
            __half2 a0 = __hmul2(W0, *(const __half2*)&A.x);
            __half2 a1 = __hmul2(W0, *(const __half2*)&A.y);
            __half2 a2 = __hmul2(W0, *(const __half2*)&A.z);
            __half2 a3 = __hmul2(W0, *(const __half2*)&A.w);
            a0 = __hfma2(W1, *(const __half2*)&B.x, a0);
            a1 = __hfma2(W1, *(const __half2*)&B.y, a1);
            a2 = __hfma2(W1, *(const __half2*)&B.z, a2);
            a3 = __hfma2(W1, *(const __half2*)&B.w, a3);

            union HI { __half2 h; int i; };
            #pragma unroll
            for (int d = 8; d <= 32; d <<= 1) {
                HI u0, u1, u2, u3, s0, s1, s2, s3;
                u0.h = a0; u1.h = a1; u2.h = a2; u3.h = a3;
                s0.i = __shfl_xor(u0.i, d, 64);
                s1.i = __shfl_xor(u1.i, d, 64);
                s2.i = __shfl_xor(u2.i, d, 64);
                s3.i = __shfl_xor(u3.i, d, 64);
                a0 = __hadd2(a0, s0.h);
                a1 = __hadd2(a1, s1.h);
                a2 = __hadd2(a2, s2.h);
                a3 = __hadd2(a3, s3.h);
            }
            if (lane < 8) {
                __half2* dst = (__half2*)&lds_out[bin * BST + lane * 8];
                dst[0] = a0; dst[1] = a1; dst[2] = a2; dst[3] = a3;
            }
        };

        const int bin_lo = (wave * PP2) >> 2;         // 0,12,24,36
        const int bin_hi = ((wave + 1) * PP2) >> 2;   // 12,24,36,49

        int o0, o1; __half2 w0, w1;
        mkbin(bin_lo, o0, o1, w0, w1);
        uint4 vA = fbase[(unsigned)o0];
        uint4 vB = fbase[(unsigned)o1];

        for (int bin = bin_lo; bin < bin_hi - 1; ++bin) {
            int no0, no1; __half2 nw0, nw1;
            mkbin(bin + 1, no0, no1, nw0, nw1);
            const uint4 pA = fbase[(unsigned)no0];   // issued before compute
            const uint4 pB = fbase[(unsigned)no1];
            compute_store(bin, vA, vB, w0, w1);
            vA = pA; vB = pB; w0 = nw0; w1 = nw1;
        }
        compute_store(bin_hi - 1, vA, vB, w0, w1);

        __syncthreads();

        // Contiguous 64*49-float output slice: out + n*12544 + cq*3136.
        float4* o4 = (float4*)(out + (size_t)n * (C_ * PP2) + (size_t)cq * (CB * PP2));
        for (int i = t; i < (CB * PP2) / 4; i += 256) {   // 784 float4
            const int l0 = i * 4;
            float4 v;
            #pragma unroll
            for (int jj = 0; jj < 4; ++jj) {
                const int l  = l0 + jj;
                const int c  = l / PP2;
                const int bn = l - c * PP2;
                ((float*)&v)[jj] = __half2float(lds_out[bn * BST + c]);
            }
            o4[i] = v;
        }
        // Next iteration's coord write happens before its __syncthreads, and
        // lds_out writes after it -> no extra barrier needed here.
    }
}

// ---------------- Fallback (NCHW direct, fp32) ------------------------------
__global__ __launch_bounds__(256)
void roi_align_kernel(const float* __restrict__ rois,
                      const float* __restrict__ feat,
                      const int* __restrict__ stride_ptr,
                      int B, int C, int H, int W, int N,
                      float* __restrict__ out) {
    const int total = N * C * POOLED * POOLED;
    int idx = blockIdx.x * blockDim.x + threadIdx.x;
    if (idx >= total) return;

    const float scale = 1.0f / (float)stride_ptr[0];

    int pw = idx % POOLED;
    int ph = (idx / POOLED) % POOLED;
    int c  = (idx / (POOLED * POOLED)) % C;
    int n  = idx / (POOLED * POOLED * C);

    const float* r = rois + (size_t)n * 5;
    int b = (int)r[0];
    float x1 = r[1] * scale;
    float y1 = r[2] * scale;
    float x2 = r[3] * scale;
    float y2 = r[4] * scale;
    float bin_w = fmaxf(x2 - x1, 1.0f) / (float)POOLED;
    float bin_h = fmaxf(y2 - y1, 1.0f) / (float)POOLED;

    const float* plane = feat + ((size_t)b * C + c) * (size_t)(H * W);

    float acc = 0.0f;
    #pragma unroll
    for (int sy = 0; sy < RATIO; ++sy) {
        float iy = ((float)(ph * RATIO + sy) + 0.5f) / (float)RATIO;
        float yy = y1 + iy * bin_h;
        bool vy = (yy > -1.0f) && (yy < (float)H);
        float cy = fminf(fmaxf(yy, 0.0f), (float)(H - 1));
        int y0 = (int)floorf(cy);
        if (y0 > H - 1) y0 = H - 1;
        int y1i = min(y0 + 1, H - 1);
        float fy = cy - (float)y0;
        float hy = 1.0f - fy;

        #pragma unroll
        for (int sx = 0; sx < RATIO; ++sx) {
            float ix = ((float)(pw * RATIO + sx) + 0.5f) / (float)RATIO;
            float xx = x1 + ix * bin_w;
            bool vx = (xx > -1.0f) && (xx < (float)W);
            if (!(vy && vx)) continue;
            float cx = fminf(fmaxf(xx, 0.0f), (float)(W - 1));
            int x0 = (int)floorf(cx);
            if (x0 > W - 1) x0 = W - 1;
            int x1i = min(x0 + 1, W - 1);
            float fx = cx - (float)x0;
            float hx = 1.0f - fx;

            float v00 = plane[y0  * W + x0 ];
            float v01 = plane[y0  * W + x1i];
            float v10 = plane[y1i * W + x0 ];
            float v11 = plane[y1i * W + x1i];

            acc += hy * hx * v00 + hy * fx * v01 + fy * hx * v10 + fy * fx * v11;
        }
    }

    out[idx] = acc * 0.25f;
}

extern "C" void kernel_launch(void* const* d_in, const int* in_sizes, int n_in,
                              void* d_out, int out_size, void* d_ws, size_t ws_size,
                              hipStream_t stream) {
    const float* rois = (const float*)d_in[0];
    const float* feat = (const float*)d_in[1];
    const int* stride_ptr = (const int*)d_in[2];

    const int N = in_sizes[0] / 5;
    const int B = in_sizes[1] / (C_ * P_);
    float* out = (float*)d_out;

    const size_t featBytes = (size_t)B * P_ * C_ * sizeof(__half);
    const size_t featAl    = (featBytes + 255) & ~(size_t)255;
    const size_t need      = featAl + (size_t)(2 * N + 2) * sizeof(int);

    if (ws_size >= need) {
        __half* featT  = (__half*)d_ws;
        int*    lists  = (int*)((char*)d_ws + featAl);   // [2][N]
        int*    counts = lists + 2 * N;                  // [2]

        dim3 tgrid(P_ / TP, C_ / TC, B);
        nchw_to_nhwc_h<<<tgrid, 256, 0, stream>>>(feat, featT);

        roi_partition<<<1, 1024, 0, stream>>>(rois, N, lists, counts);

        const int slots = N < 512 ? (N > 0 ? N : 1) : 512;
        roi_align_nhwc_h<<<8 * slots, 256, 0, stream>>>(rois, featT, stride_ptr,
                                                        lists, counts, out, N);
    } else {
        const int total = N * C_ * POOLED * POOLED;
        const int block = 256;
        const int grid = (total + block - 1) / block;
        roi_align_kernel<<<grid, block, 0, stream>>>(rois, feat, stride_ptr,
                                                     B, C_, H_, W_, N, out);
    }
}

// Round 5
// 162.130 us; speedup vs baseline: 1.0383x; 1.0383x over previous
//
#include <hip/hip_runtime.h>
#include <hip/hip_fp16.h>

#define POOLED 7
#define RATIO 2

constexpr int C_ = 256;
constexpr int H_ = 192;
constexpr int W_ = 192;
constexpr int P_ = H_ * W_;           // pixels per plane
constexpr int PP2 = POOLED * POOLED;  // 49

// ---------------- NCHW fp32 -> NHWC fp16 transpose -------------------------
constexpr int TC = 32;
constexpr int TP = 128;
constexpr int TPAD = TP + 1;

__global__ __launch_bounds__(256)
void nchw_to_nhwc_h(const float* __restrict__ in, __half* __restrict__ outT) {
    __shared__ float tile[TC][TPAD];
    const int b  = blockIdx.z;
    const int p0 = blockIdx.x * TP;
    const int c0 = blockIdx.y * TC;
    const float* src = in   + (size_t)b * C_ * P_;
    __half*      dst = outT + (size_t)b * P_ * C_;

    const int t = threadIdx.x;

    #pragma unroll
    for (int k = 0; k < 4; ++k) {
        const int q  = t + 256 * k;
        const int c  = q >> 5;
        const int pv = q & 31;
        const float4 v = *(const float4*)&src[(size_t)(c0 + c) * P_ + p0 + 4 * pv];
        tile[c][4 * pv + 0] = v.x;
        tile[c][4 * pv + 1] = v.y;
        tile[c][4 * pv + 2] = v.z;
        tile[c][4 * pv + 3] = v.w;
    }
    __syncthreads();

    #pragma unroll
    for (int k = 0; k < 2; ++k) {
        const int q  = t + 256 * k;
        const int p  = q >> 2;
        const int c8 = (q & 3) * 8;
        union { __half h[8]; float4 f; } u;
        #pragma unroll
        for (int i = 0; i < 8; ++i) u.h[i] = __float2half(tile[c8 + i][p]);
        *(float4*)&dst[(size_t)(p0 + p) * C_ + c0 + c8] = u.f;
    }
}

// ---------------- RoIAlign on NHWC fp16 ------------------------------------
// Round-4 (re-run; round-4 bench died to container infra, kernel unchanged).
// MLP/latency theory: VGPR_Count was 20/32/28/32 across rounds 0-3
// (launch_bounds(...,8) = 64-VGPR budget) -> compiler kept only ~2-4 loads in
// flight -> ~0.14 lines/cy/CU -> the invariant ~46 us. Fix:
//  * __launch_bounds__(256, 4): 128-VGPR budget, 16 waves/CU.
//  * channel-per-lane (CB=128, 2 blocks/ROI): lane owns one half2 of
//    channels; each corner read = coalesced wave-wide dword load (2 lines).
//    16 independent loads/bin into 16 distinct VGPRs -> 16 in flight/wave.
//  * NO cross-lane reduce (lane's half2 is final) -> -12 DS -12 VALU per bin.
constexpr int CB  = 128;              // channels per block
constexpr int BPR = C_ / CB;          // 2 blocks per ROI
constexpr int BST = CB + 2;           // 130 halves

__global__ __launch_bounds__(256, 4)
void roi_align_nhwc_h(const float* __restrict__ rois,
                      const __half* __restrict__ featT,   // (B,H,W,C) fp16
                      const int* __restrict__ stride_ptr,
                      float* __restrict__ out, int N) {
    __shared__ __half lds_out[PP2 * BST];  // 12740 B
    __shared__ int4 coord[28];             // [0..13]=y {lo*W, hi*W, frac*0.5, valid}
                                           // [14..27]=x {lo, hi, frac*0.5, valid}

    const int blk  = blockIdx.x;
    const int n    = blk >> 1;           // ROI index
    const int ch0  = (blk & 1) * CB;     // channel half
    const int t    = threadIdx.x;
    const int lane = t & 63;
    const int wave = t >> 6;             // 0..3

    const float scale = 1.0f / (float)stride_ptr[0];
    const float* r = rois + (size_t)n * 5;
    const int   b   = (int)r[0];
    const float rx1 = r[1] * scale;
    const float ry1 = r[2] * scale;
    const float rx2 = r[3] * scale;
    const float ry2 = r[4] * scale;
    const float bin_w = fmaxf(rx2 - rx1, 1.0f) * (1.0f / (float)POOLED);
    const float bin_h = fmaxf(ry2 - ry1, 1.0f) * (1.0f / (float)POOLED);

    if (t < 28) {
        const bool  isY   = t < 14;
        const int   s     = isY ? t : t - 14;
        const float start = isY ? ry1 : rx1;
        const float bsz   = isY ? bin_h : bin_w;
        const int   size  = isY ? H_ : W_;
        const float cc0   = start + ((float)s + 0.5f) * 0.5f * bsz;
        const bool  valid = (cc0 > -1.0f) && (cc0 < (float)size);
        float cc = fminf(fmaxf(cc0, 0.0f), (float)(size - 1));
        int lo = (int)floorf(cc);
        if (lo > size - 1) lo = size - 1;
        const int hi = min(lo + 1, size - 1);
        const float frac = (cc - (float)lo) * 0.5f;   // fold mean/4 (x*y halves)
        int4 e;
        e.x = isY ? lo * W_ : lo;
        e.y = isY ? hi * W_ : hi;
        e.z = __float_as_int(frac);
        e.w = valid ? 1 : 0;
        coord[t] = e;
    }
    __syncthreads();

    // lane's dword (= half2 = 2 channels) within each pixel's 512B record
    const uint* fb = (const uint*)featT + (size_t)b * P_ * (C_ / 2)
                                        + (ch0 >> 1) + lane;

    const int bin_lo = (wave * PP2) >> 2;         // 0,12,24,36
    const int bin_hi = ((wave + 1) * PP2) >> 2;   // 12,24,36,49

    for (int bin = bin_lo; bin < bin_hi; ++bin) {
        const int ph = bin / POOLED;
        const int pw = bin - ph * POOLED;

        const int4 cy0 = coord[2 * ph + 0];
        const int4 cy1 = coord[2 * ph + 1];
        const int4 cx0 = coord[14 + 2 * pw + 0];
        const int4 cx1 = coord[14 + 2 * pw + 1];

        const float fy0 = __int_as_float(cy0.z);
        const float fy1 = __int_as_float(cy1.z);
        const float fx0 = __int_as_float(cx0.z);
        const float fx1 = __int_as_float(cx1.z);

        const float m00 = (cy0.w & cx0.w) ? 1.0f : 0.0f;  // sample validity
        const float m01 = (cy0.w & cx1.w) ? 1.0f : 0.0f;
        const float m10 = (cy1.w & cx0.w) ? 1.0f : 0.0f;
        const float m11 = (cy1.w & cx1.w) ? 1.0f : 0.0f;

        const float wyl0 = 0.5f - fy0, wyh0 = fy0;   // 0.5-scaled bases
        const float wyl1 = 0.5f - fy1, wyh1 = fy1;
        const float wxl0 = 0.5f - fx0, wxh0 = fx0;
        const float wxl1 = 0.5f - fx1, wxh1 = fx1;

        int   pix[16];
        float wgt[16];
        // sample (y0,x0)
        pix[ 0] = cy0.x + cx0.x;  wgt[ 0] = wyl0 * wxl0 * m00;
        pix[ 1] = cy0.x + cx0.y;  wgt[ 1] = wyl0 * wxh0 * m00;
        pix[ 2] = cy0.y + cx0.x;  wgt[ 2] = wyh0 * wxl0 * m00;
        pix[ 3] = cy0.y + cx0.y;  wgt[ 3] = wyh0 * wxh0 * m00;
        // sample (y0,x1)
        pix[ 4] = cy0.x + cx1.x;  wgt[ 4] = wyl0 * wxl1 * m01;
        pix[ 5] = cy0.x + cx1.y;  wgt[ 5] = wyl0 * wxh1 * m01;
        pix[ 6] = cy0.y + cx1.x;  wgt[ 6] = wyh0 * wxl1 * m01;
        pix[ 7] = cy0.y + cx1.y;  wgt[ 7] = wyh0 * wxh1 * m01;
        // sample (y1,x0)
        pix[ 8] = cy1.x + cx0.x;  wgt[ 8] = wyl1 * wxl0 * m10;
        pix[ 9] = cy1.x + cx0.y;  wgt[ 9] = wyl1 * wxh0 * m10;
        pix[10] = cy1.y + cx0.x;  wgt[10] = wyh1 * wxl0 * m10;
        pix[11] = cy1.y + cx0.y;  wgt[11] = wyh1 * wxh0 * m10;
        // sample (y1,x1)
        pix[12] = cy1.x + cx1.x;  wgt[12] = wyl1 * wxl1 * m11;
        pix[13] = cy1.x + cx1.y;  wgt[13] = wyl1 * wxh1 * m11;
        pix[14] = cy1.y + cx1.x;  wgt[14] = wyh1 * wxl1 * m11;
        pix[15] = cy1.y + cx1.y;  wgt[15] = wyh1 * wxh1 * m11;

        // 16 independent coalesced dword gathers — all issued before any use
        uint v[16];
        #pragma unroll
        for (int k = 0; k < 16; ++k)
            v[k] = fb[(size_t)pix[k] * (C_ / 2)];

        __half2 acc = __float2half2_rn(0.f);
        #pragma unroll
        for (int k = 0; k < 16; ++k)
            acc = __hfma2(__float2half2_rn(wgt[k]), *(const __half2*)&v[k], acc);

        // lane's final half2 -> LDS (bank = lane%32, 2-way for wave64: free)
        *(__half2*)&lds_out[bin * BST + 2 * lane] = acc;
    }

    __syncthreads();

    // Contiguous 128*49-float output slice: out + n*12544 + ch0*49.
    float* obase = out + (size_t)n * (C_ * PP2) + (size_t)ch0 * PP2;
    float4* o4 = (float4*)obase;
    for (int i = t; i < (CB * PP2) / 4; i += 256) {   // 1568 float4
        const int l0 = i * 4;
        float4 v;
        #pragma unroll
        for (int j = 0; j < 4; ++j) {
            const int l  = l0 + j;
            const int c  = l / PP2;          // local channel 0..127
            const int bn = l - c * PP2;
            ((float*)&v)[j] = __half2float(lds_out[bn * BST + c]);
        }
        o4[i] = v;
    }
}

// ---------------- Fallback (NCHW direct, fp32) ------------------------------
__global__ __launch_bounds__(256)
void roi_align_kernel(const float* __restrict__ rois,
                      const float* __restrict__ feat,
                      const int* __restrict__ stride_ptr,
                      int B, int C, int H, int W, int N,
                      float* __restrict__ out) {
    const int total = N * C * POOLED * POOLED;
    int idx = blockIdx.x * blockDim.x + threadIdx.x;
    if (idx >= total) return;

    const float scale = 1.0f / (float)stride_ptr[0];

    int pw = idx % POOLED;
    int ph = (idx / POOLED) % POOLED;
    int c  = (idx / (POOLED * POOLED)) % C;
    int n  = idx / (POOLED * POOLED * C);

    const float* r = rois + (size_t)n * 5;
    int b = (int)r[0];
    float x1 = r[1] * scale;
    float y1 = r[2] * scale;
    float x2 = r[3] * scale;
    float y2 = r[4] * scale;
    float bin_w = fmaxf(x2 - x1, 1.0f) / (float)POOLED;
    float bin_h = fmaxf(y2 - y1, 1.0f) / (float)POOLED;

    const float* plane = feat + ((size_t)b * C + c) * (size_t)(H * W);

    float acc = 0.0f;
    #pragma unroll
    for (int sy = 0; sy < RATIO; ++sy) {
        float iy = ((float)(ph * RATIO + sy) + 0.5f) / (float)RATIO;
        float yy = y1 + iy * bin_h;
        bool vy = (yy > -1.0f) && (yy < (float)H);
        float cy = fminf(fmaxf(yy, 0.0f), (float)(H - 1));
        int y0 = (int)floorf(cy);
        if (y0 > H - 1) y0 = H - 1;
        int y1i = min(y0 + 1, H - 1);
        float fy = cy - (float)y0;
        float hy = 1.0f - fy;

        #pragma unroll
        for (int sx = 0; sx < RATIO; ++sx) {
            float ix = ((float)(pw * RATIO + sx) + 0.5f) / (float)RATIO;
            float xx = x1 + ix * bin_w;
            bool vx = (xx > -1.0f) && (xx < (float)W);
            if (!(vy && vx)) continue;
            float cx = fminf(fmaxf(xx, 0.0f), (float)(W - 1));
            int x0 = (int)floorf(cx);
            if (x0 > W - 1) x0 = W - 1;
            int x1i = min(x0 + 1, W - 1);
            float fx = cx - (float)x0;
            float hx = 1.0f - fx;

            float v00 = plane[y0  * W + x0 ];
            float v01 = plane[y0  * W + x1i];
            float v10 = plane[y1i * W + x0 ];
            float v11 = plane[y1i * W + x1i];

            acc += hy * hx * v00 + hy * fx * v01 + fy * hx * v10 + fy * fx * v11;
        }
    }

    out[idx] = acc * 0.25f;
}

extern "C" void kernel_launch(void* const* d_in, const int* in_sizes, int n_in,
                              void* d_out, int out_size, void* d_ws, size_t ws_size,
                              hipStream_t stream) {
    const float* rois = (const float*)d_in[0];
    const float* feat = (const float*)d_in[1];
    const int* stride_ptr = (const int*)d_in[2];

    const int N = in_sizes[0] / 5;
    const int B = in_sizes[1] / (C_ * P_);
    float* out = (float*)d_out;

    const size_t need = (size_t)B * P_ * C_ * sizeof(__half);
    if (ws_size >= need) {
        __half* featT = (__half*)d_ws;
        dim3 tgrid(P_ / TP, C_ / TC, B);
        nchw_to_nhwc_h<<<tgrid, 256, 0, stream>>>(feat, featT);

        roi_align_nhwc_h<<<N * BPR, 256, 0, stream>>>(rois, featT, stride_ptr,
                                                      out, N);
    } else {
        const int total = N * C_ * POOLED * POOLED;
        const int block = 256;
        const int grid = (total + block - 1) / block;
        roi_align_kernel<<<grid, block, 0, stream>>>(rois, feat, stride_ptr,
                                                     B, C_, H_, W_, N, out);
    }
}